// Round 6
// baseline (77.607 us; speedup 1.0000x reference)
//
#include <hip/hip_runtime.h>
#include <hip/hip_bf16.h>
#include <math.h>

#define NFEAT 16
#define NRULE 64
#define RQUADS 13    // float4s per rule block (52 floats)
#define RPW 16       // rules per wave
#define WPB 4        // waves per block

// Packed per-rule block (13 x float4, base = cst + r*52 floats):
//   q0..q3  : negc[a]  = -log2(e)/(2*sigma^2)        (a = 0..15)
//   q4..q7  : cmu2[a]  =  log2(e)*mu/sigma^2
//   q8..q11 : rho_a[a] =  rho[r][a]
//   q12     : { bias, K = -log2(e)*sum mu^2/(2sigma^2), 0, 0 }
// Gaussian Horner form: l = K + sum_a (negc[a]*x + cmu2[a])*x;  w = exp2(l).
__global__ void fuzzy_prep(const float* __restrict__ mu,
                           const float* __restrict__ sigma,
                           const float* __restrict__ rho,
                           float* __restrict__ cst) {
    const float L2E = 1.4426950408889634f;
    int r = threadIdx.x;
    if (r >= NRULE) return;
    float* c = cst + r * (RQUADS * 4);
    float K = 0.0f;
#pragma unroll
    for (int a = 0; a < NFEAT; ++a) {
        float m = mu[r * NFEAT + a];
        float s = sigma[r * NFEAT + a];
        float inv = 1.0f / (2.0f * s * s);
        c[a]      = -inv * L2E;
        c[16 + a] = 2.0f * inv * m * L2E;
        c[32 + a] = rho[r * (NFEAT + 1) + a];
        K         = fmaf(-inv * m, m, K);
    }
    c[48] = rho[r * (NFEAT + 1) + NFEAT];
    c[49] = K * L2E;
    c[50] = 0.0f;
    c[51] = 0.0f;
}

// Block = 256 threads = 4 waves, 64 samples (sample = lane). Wave q handles
// rules [16q,16q+16). Rule constants staged once into LDS; in-loop reads use
// wave-uniform addresses -> ds_read_b128 broadcast (in-order completion, fine
// lgkmcnt, offsets in the 16-bit DS immediate). This replaces the SMEM path,
// whose out-of-order returns force lgkmcnt(0) drains per unroll batch.
__global__ __launch_bounds__(256) void fuzzy_main(const float* __restrict__ x,
                                                  const float* __restrict__ cst,
                                                  float* __restrict__ out,
                                                  int n) {
    __shared__ float4 cl[NRULE * RQUADS];          // 13312 B
    __shared__ float pnum[WPB][64];                // 1024 B
    __shared__ float pden[WPB][64];                // 1024 B

    const int tid  = threadIdx.x;
    const int lane = tid & 63;
    const int q    = __builtin_amdgcn_readfirstlane(tid >> 6);
    const int k    = blockIdx.x * 64 + lane;
    const int kc   = k < n ? k : n - 1;

    // Stage all 64 rule blocks (832 float4s) cooperatively.
    const float4* cg = (const float4*)cst;
#pragma unroll
    for (int i = 0; i < 4; ++i) {
        int idx = tid + i * 256;
        if (idx < NRULE * RQUADS) cl[idx] = cg[idx];
    }

    // 16 features per sample: 4 x float4, 64 B/thread, coalesced.
    const float4* x4 = (const float4*)(x + (size_t)kc * NFEAT);
    float4 v0 = x4[0], v1 = x4[1], v2 = x4[2], v3 = x4[3];
    float xs[NFEAT] = {v0.x, v0.y, v0.z, v0.w,
                       v1.x, v1.y, v1.z, v1.w,
                       v2.x, v2.y, v2.z, v2.w,
                       v3.x, v3.y, v3.z, v3.w};

    __syncthreads();

    float num = 0.0f, den = 0.0f;
    const float4* cb = cl + q * (RPW * RQUADS);    // wave-uniform base
#pragma unroll 2
    for (int r = 0; r < RPW; ++r) {
        const float4* c = cb + r * RQUADS;
        float4 n0 = c[0], n1 = c[1], n2 = c[2], n3 = c[3];     // negc
        float4 m0 = c[4], m1 = c[5], m2 = c[6], m3 = c[7];     // cmu2
        float4 r0 = c[8], r1 = c[9], r2 = c[10], r3 = c[11];   // rho
        float4 tl = c[12];                                     // bias, K
        float nc[NFEAT]  = {n0.x,n0.y,n0.z,n0.w, n1.x,n1.y,n1.z,n1.w,
                            n2.x,n2.y,n2.z,n2.w, n3.x,n3.y,n3.z,n3.w};
        float cm[NFEAT]  = {m0.x,m0.y,m0.z,m0.w, m1.x,m1.y,m1.z,m1.w,
                            m2.x,m2.y,m2.z,m2.w, m3.x,m3.y,m3.z,m3.w};
        float rh[NFEAT]  = {r0.x,r0.y,r0.z,r0.w, r1.x,r1.y,r1.z,r1.w,
                            r2.x,r2.y,r2.z,r2.w, r3.x,r3.y,r3.z,r3.w};
        float z  = tl.x;
        float l0 = tl.y, l1 = 0.0f;                // two chains for ILP
#pragma unroll
        for (int a = 0; a < NFEAT; a += 2) {
            float t0 = fmaf(nc[a],     xs[a],     cm[a]);
            float t1 = fmaf(nc[a + 1], xs[a + 1], cm[a + 1]);
            l0 = fmaf(t0, xs[a],     l0);
            l1 = fmaf(t1, xs[a + 1], l1);
            z  = fmaf(rh[a],     xs[a],     z);
            z  = fmaf(rh[a + 1], xs[a + 1], z);
        }
        float w = __builtin_amdgcn_exp2f(l0 + l1); // one v_exp_f32
        num = fmaf(z, w, num);
        den += w;
    }

    pnum[q][lane] = num;
    pden[q][lane] = den;
    __syncthreads();
    if (q == 0 && k < n) {
        float nn = pnum[0][lane] + pnum[1][lane] + pnum[2][lane] + pnum[3][lane];
        float dd = pden[0][lane] + pden[1][lane] + pden[2][lane] + pden[3][lane];
        out[k] = nn / (dd + 1e-13f);
    }
}

extern "C" void kernel_launch(void* const* d_in, const int* in_sizes, int n_in,
                              void* d_out, int out_size, void* d_ws, size_t ws_size,
                              hipStream_t stream) {
    const float* x     = (const float*)d_in[0];   // [N,16]
    const float* mu    = (const float*)d_in[1];   // [64,16]
    const float* sigma = (const float*)d_in[2];   // [64,16]
    const float* rho   = (const float*)d_in[3];   // [64,17]
    float* out = (float*)d_out;
    float* cst = (float*)d_ws;                    // 64*52*4 = 13312 B used

    int n = in_sizes[0] / NFEAT;                  // 131072

    fuzzy_prep<<<1, 64, 0, stream>>>(mu, sigma, rho, cst);
    fuzzy_main<<<(n + 63) / 64, 256, 0, stream>>>(x, cst, out, n);
}

// Round 7
// 75.825 us; speedup vs baseline: 1.0235x; 1.0235x over previous
//
#include <hip/hip_runtime.h>
#include <math.h>

#define NFEAT 16
#define NRULE 64
#define RQUADS 13    // float4s per rule block (52 floats)
#define RPW 16       // rules per wave
#define WPB 4        // waves per block
#define SPL 4        // samples per lane (constant-read amortization)

// Per-rule block (13 x float4, base = cst + r*52 floats):
//   q0..q3  : negc[a] = -log2(e)/(2*sigma_ra^2)          (general path)
//   q4..q7  : B[a]    =  log2(e)*mu_ra/sigma_ra^2        (both paths)
//   q8..q11 : rho[a]
//   q12     : { bias, KL = -log2(e)*sum mu^2/(2s^2), P = -log2(e)/(2s^2), 0 }
// cst[64*52] : flag = 1 if every rule's 1/(2s^2) is feature-uniform (exact).
// Fast path (flag): logw*log2e = P*Q + sum_a B[a]*x_a + KL,  Q = sum x^2.
__global__ void fuzzy_prep(const float* __restrict__ mu,
                           const float* __restrict__ sigma,
                           const float* __restrict__ rho,
                           float* __restrict__ cst) {
    const float L2E = 1.4426950408889634f;
    __shared__ int uni[NRULE];
    int r = threadIdx.x;
    if (r < NRULE) {
        float* c = cst + r * 52;
        float s0 = sigma[r * NFEAT];
        float c0 = 1.0f / (2.0f * s0 * s0);
        float K = 0.0f;
        int u = 1;
        for (int a = 0; a < NFEAT; ++a) {
            float m = mu[r * NFEAT + a];
            float s = sigma[r * NFEAT + a];
            float inv = 1.0f / (2.0f * s * s);
            if (inv != c0) u = 0;
            c[a]      = -inv * L2E;
            c[16 + a] = 2.0f * inv * m * L2E;
            c[32 + a] = rho[r * (NFEAT + 1) + a];
            K         = fmaf(-inv * m, m, K);
        }
        c[48] = rho[r * (NFEAT + 1) + NFEAT];
        c[49] = K * L2E;
        c[50] = -c0 * L2E;
        c[51] = 0.0f;
        uni[r] = u;
    }
    __syncthreads();
    if (r == 0) {
        int f = 1;
        for (int i = 0; i < NRULE; ++i) f &= uni[i];
        cst[NRULE * 52] = (float)f;
    }
}

// Block = 256 threads = 4 waves; block covers 256 samples (4 per lane).
// Wave q handles rules [16q,16q+16) for all 256; LDS combine at the end.
__global__ __launch_bounds__(256, 2) void fuzzy_main(const float* __restrict__ x,
                                                     const float* __restrict__ cst,
                                                     float* __restrict__ out,
                                                     int n) {
    __shared__ float4 cl[NRULE * RQUADS];          // 13312 B
    __shared__ float pnum[WPB][256];               // 4096 B
    __shared__ float pden[WPB][256];               // 4096 B

    const int tid  = threadIdx.x;
    const int lane = tid & 63;
    const int q    = __builtin_amdgcn_readfirstlane(tid >> 6);
    const int base = blockIdx.x * (64 * SPL);

    // Stage all rule constants (832 quads) cooperatively.
    const float4* cg = (const float4*)cst;
    for (int i = tid; i < NRULE * RQUADS; i += 256) cl[i] = cg[i];
    const int flag = (int)cst[NRULE * 52];         // uniform scalar load

    // Load 4 samples/lane (each 4 x float4, coalesced) + per-sample Q.
    float xs[SPL][NFEAT];
    float Qs[SPL];
#pragma unroll
    for (int s = 0; s < SPL; ++s) {
        int k = base + s * 64 + lane;
        int kc = k < n ? k : n - 1;
        const float4* x4 = (const float4*)(x + (size_t)kc * NFEAT);
        float4 a = x4[0], b = x4[1], c = x4[2], d = x4[3];
        float* p = xs[s];
        p[0]=a.x; p[1]=a.y; p[2]=a.z; p[3]=a.w;
        p[4]=b.x; p[5]=b.y; p[6]=b.z; p[7]=b.w;
        p[8]=c.x; p[9]=c.y; p[10]=c.z; p[11]=c.w;
        p[12]=d.x; p[13]=d.y; p[14]=d.z; p[15]=d.w;
        float qq = 0.0f;
#pragma unroll
        for (int a2 = 0; a2 < NFEAT; ++a2) qq = fmaf(p[a2], p[a2], qq);
        Qs[s] = qq;
    }
    __syncthreads();

    float num[SPL] = {0, 0, 0, 0}, den[SPL] = {0, 0, 0, 0};
    const float4* cb = cl + q * (RPW * RQUADS);    // wave-uniform base

    if (flag) {
        // Fast path: 2 FMA/feature/sample, 9 quads/rule.
#pragma unroll 2
        for (int r = 0; r < RPW; ++r) {
            const float4* c = cb + r * RQUADS;
            float4 b0 = c[4], b1 = c[5], b2 = c[6], b3 = c[7];     // B
            float4 r0 = c[8], r1 = c[9], r2 = c[10], r3 = c[11];   // rho
            float4 tl = c[12];                                     // bias,KL,P
            float B[NFEAT]  = {b0.x,b0.y,b0.z,b0.w, b1.x,b1.y,b1.z,b1.w,
                               b2.x,b2.y,b2.z,b2.w, b3.x,b3.y,b3.z,b3.w};
            float rh[NFEAT] = {r0.x,r0.y,r0.z,r0.w, r1.x,r1.y,r1.z,r1.w,
                               r2.x,r2.y,r2.z,r2.w, r3.x,r3.y,r3.z,r3.w};
            float z[SPL], l[SPL];
#pragma unroll
            for (int s = 0; s < SPL; ++s) {
                z[s] = tl.x;
                l[s] = fmaf(tl.z, Qs[s], tl.y);    // P*Q + KL
            }
#pragma unroll
            for (int a = 0; a < NFEAT; ++a) {
#pragma unroll
                for (int s = 0; s < SPL; ++s) {
                    l[s] = fmaf(B[a],  xs[s][a], l[s]);
                    z[s] = fmaf(rh[a], xs[s][a], z[s]);
                }
            }
#pragma unroll
            for (int s = 0; s < SPL; ++s) {
                float w = __builtin_amdgcn_exp2f(l[s]);
                num[s] = fmaf(z[s], w, num[s]);
                den[s] += w;
            }
        }
    } else {
        // General path: 3 FMA/feature/sample (arbitrary sigma).
#pragma unroll 2
        for (int r = 0; r < RPW; ++r) {
            const float4* c = cb + r * RQUADS;
            float4 n0 = c[0], n1 = c[1], n2 = c[2], n3 = c[3];
            float4 m0 = c[4], m1 = c[5], m2 = c[6], m3 = c[7];
            float4 r0 = c[8], r1 = c[9], r2 = c[10], r3 = c[11];
            float4 tl = c[12];
            float nc[NFEAT] = {n0.x,n0.y,n0.z,n0.w, n1.x,n1.y,n1.z,n1.w,
                               n2.x,n2.y,n2.z,n2.w, n3.x,n3.y,n3.z,n3.w};
            float cm[NFEAT] = {m0.x,m0.y,m0.z,m0.w, m1.x,m1.y,m1.z,m1.w,
                               m2.x,m2.y,m2.z,m2.w, m3.x,m3.y,m3.z,m3.w};
            float rh[NFEAT] = {r0.x,r0.y,r0.z,r0.w, r1.x,r1.y,r1.z,r1.w,
                               r2.x,r2.y,r2.z,r2.w, r3.x,r3.y,r3.z,r3.w};
            float z[SPL], l[SPL];
#pragma unroll
            for (int s = 0; s < SPL; ++s) { z[s] = tl.x; l[s] = tl.y; }
#pragma unroll
            for (int a = 0; a < NFEAT; ++a) {
#pragma unroll
                for (int s = 0; s < SPL; ++s) {
                    float t = fmaf(nc[a], xs[s][a], cm[a]);
                    l[s] = fmaf(t, xs[s][a], l[s]);
                    z[s] = fmaf(rh[a], xs[s][a], z[s]);
                }
            }
#pragma unroll
            for (int s = 0; s < SPL; ++s) {
                float w = __builtin_amdgcn_exp2f(l[s]);
                num[s] = fmaf(z[s], w, num[s]);
                den[s] += w;
            }
        }
    }

#pragma unroll
    for (int s = 0; s < SPL; ++s) {
        pnum[q][s * 64 + lane] = num[s];
        pden[q][s * 64 + lane] = den[s];
    }
    __syncthreads();
    {
        int k = base + tid;
        if (k < n) {
            float nn = pnum[0][tid] + pnum[1][tid] + pnum[2][tid] + pnum[3][tid];
            float dd = pden[0][tid] + pden[1][tid] + pden[2][tid] + pden[3][tid];
            out[k] = nn / (dd + 1e-13f);
        }
    }
}

extern "C" void kernel_launch(void* const* d_in, const int* in_sizes, int n_in,
                              void* d_out, int out_size, void* d_ws, size_t ws_size,
                              hipStream_t stream) {
    const float* x     = (const float*)d_in[0];   // [N,16]
    const float* mu    = (const float*)d_in[1];   // [64,16]
    const float* sigma = (const float*)d_in[2];   // [64,16]
    const float* rho   = (const float*)d_in[3];   // [64,17]
    float* out = (float*)d_out;
    float* cst = (float*)d_ws;                    // 64*52+1 floats used

    int n = in_sizes[0] / NFEAT;                  // 131072

    fuzzy_prep<<<1, 64, 0, stream>>>(mu, sigma, rho, cst);
    int blocks = (n + 64 * SPL - 1) / (64 * SPL); // 512
    fuzzy_main<<<blocks, 256, 0, stream>>>(x, cst, out, n);
}

// Round 8
// 72.670 us; speedup vs baseline: 1.0680x; 1.0434x over previous
//
#include <hip/hip_runtime.h>
#include <math.h>

#define NFEAT 16
#define NRULE 64
#define RQUADS 13    // float4s per rule block (52 floats)
#define RPW 16       // rules per wave
#define WPB 4        // waves per block
#define SPL 4        // samples per lane

// Single fused kernel. Per-rule LDS block (13 x float4, base = r*52 floats):
//   q0..q3  : negc[a] = -log2(e)/(2*sigma_ra^2)          (general path)
//   q4..q7  : B[a]    =  log2(e)*mu_ra/sigma_ra^2        (both paths)
//   q8..q11 : rho[a]
//   q12     : { bias, KL = -log2(e)*sum mu^2/(2s^2), P = -log2(e)/(2s^2), 0 }
// Fast path (sigma feature-uniform, detected exactly via ballot):
//   logw*log2e = P*Q + sum_a B[a]*x_a + KL,   Q = sum_a x_a^2.
__global__ __launch_bounds__(256, 2) void fuzzy_fused(const float* __restrict__ x,
                                                      const float* __restrict__ mu,
                                                      const float* __restrict__ sigma,
                                                      const float* __restrict__ rho,
                                                      float* __restrict__ out,
                                                      int n) {
    __shared__ float4 cl[NRULE * RQUADS];          // 13312 B
    __shared__ float pnum[WPB][256];               // 4096 B
    __shared__ float pden[WPB][256];               // 4096 B
    __shared__ float flag_lds;

    const int tid  = threadIdx.x;
    const int lane = tid & 63;
    const int q    = __builtin_amdgcn_readfirstlane(tid >> 6);
    const int base = blockIdx.x * (64 * SPL);

    // --- x loads first so they're in flight during in-block prep ---
    float xs[SPL][NFEAT];
    float Qs[SPL];
#pragma unroll
    for (int s = 0; s < SPL; ++s) {
        int k = base + s * 64 + lane;
        int kc = k < n ? k : n - 1;
        const float4* x4 = (const float4*)(x + (size_t)kc * NFEAT);
        float4 a = x4[0], b = x4[1], c = x4[2], d = x4[3];
        float* p = xs[s];
        p[0]=a.x; p[1]=a.y; p[2]=a.z; p[3]=a.w;
        p[4]=b.x; p[5]=b.y; p[6]=b.z; p[7]=b.w;
        p[8]=c.x; p[9]=c.y; p[10]=c.z; p[11]=c.w;
        p[12]=d.x; p[13]=d.y; p[14]=d.z; p[15]=d.w;
        float qq = 0.0f;
#pragma unroll
        for (int a2 = 0; a2 < NFEAT; ++a2) qq = fmaf(p[a2], p[a2], qq);
        Qs[s] = qq;
    }

    // --- in-block prep: wave 0, lane = rule. Replaces the prep dispatch
    //     (whose serial r==0 loop + cold reads + graph gap were fixed cost).
    if (tid < NRULE) {
        int r = tid;
        float* c = (float*)cl + r * 52;
        const float L2E = 1.4426950408889634f;
        float s0 = sigma[r * NFEAT];
        float c0 = 1.0f / (2.0f * s0 * s0);
        float K = 0.0f;
        bool u = true;
#pragma unroll
        for (int a = 0; a < NFEAT; ++a) {
            float m = mu[r * NFEAT + a];
            float s = sigma[r * NFEAT + a];
            float inv = 1.0f / (2.0f * s * s);
            u = u && (inv == c0);
            c[a]      = -inv * L2E;
            c[16 + a] = 2.0f * inv * m * L2E;
            c[32 + a] = rho[r * (NFEAT + 1) + a];
            K         = fmaf(-inv * m, m, K);
        }
        c[48] = rho[r * (NFEAT + 1) + NFEAT];
        c[49] = K * L2E;
        c[50] = -c0 * L2E;
        c[51] = 0.0f;
        unsigned long long b = __ballot(u);        // uniformity across rules
        if (tid == 0) flag_lds = (b == ~0ull) ? 1.0f : 0.0f;
    }
    __syncthreads();
    const int flag = __builtin_amdgcn_readfirstlane((int)flag_lds);

    float num[SPL] = {0, 0, 0, 0}, den[SPL] = {0, 0, 0, 0};
    const float4* cb = cl + q * (RPW * RQUADS);    // wave-uniform base

    if (flag) {
        // Fast path: 2 FMA/feature/sample.
#pragma unroll 2
        for (int r = 0; r < RPW; ++r) {
            const float4* c = cb + r * RQUADS;
            float4 b0 = c[4], b1 = c[5], b2 = c[6], b3 = c[7];     // B
            float4 r0 = c[8], r1 = c[9], r2 = c[10], r3 = c[11];   // rho
            float4 tl = c[12];                                     // bias,KL,P
            float B[NFEAT]  = {b0.x,b0.y,b0.z,b0.w, b1.x,b1.y,b1.z,b1.w,
                               b2.x,b2.y,b2.z,b2.w, b3.x,b3.y,b3.z,b3.w};
            float rh[NFEAT] = {r0.x,r0.y,r0.z,r0.w, r1.x,r1.y,r1.z,r1.w,
                               r2.x,r2.y,r2.z,r2.w, r3.x,r3.y,r3.z,r3.w};
            float z[SPL], l[SPL];
#pragma unroll
            for (int s = 0; s < SPL; ++s) {
                z[s] = tl.x;
                l[s] = fmaf(tl.z, Qs[s], tl.y);    // P*Q + KL
            }
#pragma unroll
            for (int a = 0; a < NFEAT; ++a) {
#pragma unroll
                for (int s = 0; s < SPL; ++s) {
                    l[s] = fmaf(B[a],  xs[s][a], l[s]);
                    z[s] = fmaf(rh[a], xs[s][a], z[s]);
                }
            }
#pragma unroll
            for (int s = 0; s < SPL; ++s) {
                float w = __builtin_amdgcn_exp2f(l[s]);
                num[s] = fmaf(z[s], w, num[s]);
                den[s] += w;
            }
        }
    } else {
        // General path: 3 FMA/feature/sample (arbitrary sigma).
#pragma unroll 2
        for (int r = 0; r < RPW; ++r) {
            const float4* c = cb + r * RQUADS;
            float4 n0 = c[0], n1 = c[1], n2 = c[2], n3 = c[3];
            float4 m0 = c[4], m1 = c[5], m2 = c[6], m3 = c[7];
            float4 r0 = c[8], r1 = c[9], r2 = c[10], r3 = c[11];
            float4 tl = c[12];
            float nc[NFEAT] = {n0.x,n0.y,n0.z,n0.w, n1.x,n1.y,n1.z,n1.w,
                               n2.x,n2.y,n2.z,n2.w, n3.x,n3.y,n3.z,n3.w};
            float cm[NFEAT] = {m0.x,m0.y,m0.z,m0.w, m1.x,m1.y,m1.z,m1.w,
                               m2.x,m2.y,m2.z,m2.w, m3.x,m3.y,m3.z,m3.w};
            float rh[NFEAT] = {r0.x,r0.y,r0.z,r0.w, r1.x,r1.y,r1.z,r1.w,
                               r2.x,r2.y,r2.z,r2.w, r3.x,r3.y,r3.z,r3.w};
            float z[SPL], l[SPL];
#pragma unroll
            for (int s = 0; s < SPL; ++s) { z[s] = tl.x; l[s] = tl.y; }
#pragma unroll
            for (int a = 0; a < NFEAT; ++a) {
#pragma unroll
                for (int s = 0; s < SPL; ++s) {
                    float t = fmaf(nc[a], xs[s][a], cm[a]);
                    l[s] = fmaf(t, xs[s][a], l[s]);
                    z[s] = fmaf(rh[a], xs[s][a], z[s]);
                }
            }
#pragma unroll
            for (int s = 0; s < SPL; ++s) {
                float w = __builtin_amdgcn_exp2f(l[s]);
                num[s] = fmaf(z[s], w, num[s]);
                den[s] += w;
            }
        }
    }

#pragma unroll
    for (int s = 0; s < SPL; ++s) {
        pnum[q][s * 64 + lane] = num[s];
        pden[q][s * 64 + lane] = den[s];
    }
    __syncthreads();
    {
        int k = base + tid;
        if (k < n) {
            float nn = pnum[0][tid] + pnum[1][tid] + pnum[2][tid] + pnum[3][tid];
            float dd = pden[0][tid] + pden[1][tid] + pden[2][tid] + pden[3][tid];
            out[k] = nn / (dd + 1e-13f);
        }
    }
}

extern "C" void kernel_launch(void* const* d_in, const int* in_sizes, int n_in,
                              void* d_out, int out_size, void* d_ws, size_t ws_size,
                              hipStream_t stream) {
    const float* x     = (const float*)d_in[0];   // [N,16]
    const float* mu    = (const float*)d_in[1];   // [64,16]
    const float* sigma = (const float*)d_in[2];   // [64,16]
    const float* rho   = (const float*)d_in[3];   // [64,17]
    float* out = (float*)d_out;

    int n = in_sizes[0] / NFEAT;                  // 131072

    int blocks = (n + 64 * SPL - 1) / (64 * SPL); // 512
    fuzzy_fused<<<blocks, 256, 0, stream>>>(x, mu, sigma, rho, out, n);
}

// Round 9
// 70.174 us; speedup vs baseline: 1.1059x; 1.0356x over previous
//
#include <hip/hip_runtime.h>
#include <math.h>

#define NFEAT 16
#define NRULE 64
#define ROWDW 80              // dwords per lane-row in the frag table
#define FLAG_DW (64 * ROWDW)  // sigma-uniform flag slot (table end)

typedef _Float16 half8 __attribute__((ext_vector_type(8)));
typedef float    f4    __attribute__((ext_vector_type(4)));
union F4H8 { float4 f; half8 h; };

// ---------------------------------------------------------------------------
// Prep: build per-lane MFMA B-operand fragment table in d_ws.
// Lane row (80 dwords): [0:16) B1=[Bh;Bh] frags T=0..3 (4 dw each)
//                       [16:32) B2=[Bl;Bl]  [32:48) R1=[Rh;Rh]  [48:64) R2=[Rl;Rl]
//                       [64:68) P[T]  [68:72) KL[T]  [72:76) bias[T]
// B-frag lane layout: n = lane&15 (rule within tile), k = quad*8+j.
// K=32 packs the f16 split: A = [Xh | Xl]; B1 = [Wh;Wh]; B2 = [Wl;Wl]
//   => mfma(A,B1) + mfma(A,B2) = Xh*Wh + Xl*Wh + Xh*Wl + Xl*Wl.
// Bw = 2*inv*mu*log2e ; P = -inv*log2e ; KL = -log2e*sum inv*mu^2.
// ---------------------------------------------------------------------------
__global__ void fuzzy_prep(const float* __restrict__ mu,
                           const float* __restrict__ sigma,
                           const float* __restrict__ rho,
                           float* __restrict__ tab) {
    const float L2E = 1.4426950408889634f;
    __shared__ int u_sh[256];
    int t = threadIdx.x;
    int L = t & 63, T = t >> 6;
    int n = L & 15, quad = L >> 4;
    int rule = T * 16 + n;
    int fb = (quad & 1) * 8;      // feats this lane's k-slots map to

    F4H8 b1, b2, r1, r2;
#pragma unroll
    for (int j = 0; j < 8; ++j) {
        int f = fb + j;
        float m = mu[rule * NFEAT + f];
        float s = sigma[rule * NFEAT + f];
        float inv = 1.0f / (2.0f * s * s);
        float Bw = 2.0f * inv * m * L2E;
        _Float16 bh = (_Float16)Bw;
        b1.h[j] = bh;
        b2.h[j] = (_Float16)(Bw - (float)bh);
        float Rw = rho[rule * (NFEAT + 1) + f];
        _Float16 rh = (_Float16)Rw;
        r1.h[j] = rh;
        r2.h[j] = (_Float16)(Rw - (float)rh);
    }
    float* rowp = tab + L * ROWDW;
    ((float4*)rowp)[T]      = b1.f;
    ((float4*)rowp)[4 + T]  = b2.f;
    ((float4*)rowp)[8 + T]  = r1.f;
    ((float4*)rowp)[12 + T] = r2.f;

    float s0 = sigma[rule * NFEAT];
    float c0 = 1.0f / (2.0f * s0 * s0);
    float K = 0.0f;
    int u = 1;
#pragma unroll
    for (int a = 0; a < NFEAT; ++a) {
        float m = mu[rule * NFEAT + a];
        float s = sigma[rule * NFEAT + a];
        float inv = 1.0f / (2.0f * s * s);
        if (inv != c0) u = 0;
        K = fmaf(-inv * m, m, K);
    }
    rowp[64 + T] = -c0 * L2E;                  // P
    rowp[68 + T] = K * L2E;                    // KL
    rowp[72 + T] = rho[rule * (NFEAT + 1) + NFEAT];  // bias

    u_sh[t] = u;
    __syncthreads();
    if (t < 64) {
        int uu = u_sh[t] & u_sh[t + 64] & u_sh[t + 128] & u_sh[t + 192];
        unsigned long long b = __ballot(uu != 0);
        if (t == 0) tab[FLAG_DW] = (b == ~0ull) ? 1.0f : 0.0f;
    }
}

// ---------------------------------------------------------------------------
// Main: 1024 blocks x 256 thr; each wave is self-contained (no LDS, no sync):
// 2 tiles of 16 samples, all 64 rules via 4 N-tiles x 4 mfma each.
// A-frag: lane = (m = lane&15 sample, k = quad*8+j); quads 0,1 = Xh, 2,3 = Xl.
// C/D: col = lane&15 (rule), row = quad*4+reg (sample)  [m89-verified mapping]
// ---------------------------------------------------------------------------
__global__ __launch_bounds__(256, 4) void fuzzy_main(const float* __restrict__ x,
                                                     const float* __restrict__ tab,
                                                     const float* __restrict__ mu,
                                                     const float* __restrict__ sigma,
                                                     const float* __restrict__ rho,
                                                     float* __restrict__ out, int n) {
    const int tid  = threadIdx.x;
    const int L    = tid & 63;
    const int quad = L >> 4;
    const int wv   = __builtin_amdgcn_readfirstlane(tid >> 6);
    const int flag = __builtin_amdgcn_readfirstlane((int)tab[FLAG_DW]);
    const int m    = L & 15;
    const int fb   = (quad & 1) * 8;

    if (flag) {
        const float4* row = (const float4*)(tab + L * ROWDW);
        F4H8 b1[4], b2[4], r1[4], r2[4];
#pragma unroll
        for (int T = 0; T < 4; ++T) {
            b1[T].f = row[T];      b2[T].f = row[4 + T];
            r1[T].f = row[8 + T];  r2[T].f = row[12 + T];
        }
        float4 Pq = row[16], Kq = row[17], Bq = row[18];
        float PvA[4]  = {Pq.x, Pq.y, Pq.z, Pq.w};
        float KLvA[4] = {Kq.x, Kq.y, Kq.z, Kq.w};
        float BvA[4]  = {Bq.x, Bq.y, Bq.z, Bq.w};

#pragma unroll
        for (int it = 0; it < 2; ++it) {
            int gt = (blockIdx.x * 4 + wv) * 2 + it;
            int tb = gt * 16;
            if (tb >= n) break;
            const float4* xp = (const float4*)(x + (size_t)(tb + m) * NFEAT + fb);
            float4 xa = xp[0], xb = xp[1];
            float xv[8] = {xa.x, xa.y, xa.z, xa.w, xb.x, xb.y, xb.z, xb.w};
            F4H8 af;
            float qp = 0.0f;
#pragma unroll
            for (int j = 0; j < 8; ++j) {
                _Float16 h = (_Float16)xv[j];
                af.h[j] = (quad < 2) ? h : (_Float16)(xv[j] - (float)h);
                qp = fmaf(xv[j], xv[j], qp);
            }
            float Qf = qp + __shfl_xor(qp, 16);   // Q[sample m], all lanes
            float Qr[4];
#pragma unroll
            for (int p = 0; p < 4; ++p) Qr[p] = __shfl(Qf, quad * 4 + p);

            f4 nsum = {0.f, 0.f, 0.f, 0.f}, dsum = {0.f, 0.f, 0.f, 0.f};
#pragma unroll
            for (int T = 0; T < 4; ++T) {
                f4 z4 = {0.f, 0.f, 0.f, 0.f};
                f4 accL = __builtin_amdgcn_mfma_f32_16x16x32_f16(af.h, b1[T].h, z4, 0, 0, 0);
                accL    = __builtin_amdgcn_mfma_f32_16x16x32_f16(af.h, b2[T].h, accL, 0, 0, 0);
                f4 accZ = __builtin_amdgcn_mfma_f32_16x16x32_f16(af.h, r1[T].h, z4, 0, 0, 0);
                accZ    = __builtin_amdgcn_mfma_f32_16x16x32_f16(af.h, r2[T].h, accZ, 0, 0, 0);
#pragma unroll
                for (int p = 0; p < 4; ++p) {
                    float l = fmaf(PvA[T], Qr[p], accL[p] + KLvA[T]);
                    float w = __builtin_amdgcn_exp2f(l);
                    float zf = accZ[p] + BvA[T];
                    nsum[p] = fmaf(zf, w, nsum[p]);
                    dsum[p] += w;
                }
            }
            // reduce over the 16 rule-columns (lanes differing in low 4 bits)
#pragma unroll
            for (int d = 1; d < 16; d <<= 1) {
#pragma unroll
                for (int p = 0; p < 4; ++p) {
                    nsum[p] += __shfl_xor(nsum[p], d);
                    dsum[p] += __shfl_xor(dsum[p], d);
                }
            }
            if ((L & 15) == 0) {   // 4 writer lanes; rows quad*4+p
                float4 o;
                o.x = nsum[0] * __builtin_amdgcn_rcpf(dsum[0] + 1e-13f);
                o.y = nsum[1] * __builtin_amdgcn_rcpf(dsum[1] + 1e-13f);
                o.z = nsum[2] * __builtin_amdgcn_rcpf(dsum[2] + 1e-13f);
                o.w = nsum[3] * __builtin_amdgcn_rcpf(dsum[3] + 1e-13f);
                ((float4*)(out + tb))[quad] = o;
            }
        }
    } else {
        // General fallback (arbitrary sigma; never taken for this input).
        const float L2E = 1.4426950408889634f;
#pragma unroll
        for (int it = 0; it < 2; ++it) {
            int gt = (blockIdx.x * 4 + wv) * 2 + it;
            int tb = gt * 16;
            if (tb >= n) break;
            int s = tb + m;
            const float4* xp = (const float4*)(x + (size_t)s * NFEAT);
            float4 a = xp[0], b = xp[1], c = xp[2], d = xp[3];
            float xs[NFEAT] = {a.x,a.y,a.z,a.w, b.x,b.y,b.z,b.w,
                               c.x,c.y,c.z,c.w, d.x,d.y,d.z,d.w};
            float num = 0.0f, den = 0.0f;
            for (int r = quad * 16; r < quad * 16 + 16; ++r) {
                float z = rho[r * (NFEAT + 1) + NFEAT];
                float l = 0.0f;
                for (int aa = 0; aa < NFEAT; ++aa) {
                    float mm = mu[r * NFEAT + aa];
                    float ss = sigma[r * NFEAT + aa];
                    float inv = 1.0f / (2.0f * ss * ss);
                    float dd = xs[aa] - mm;
                    l = fmaf(-inv * dd, dd, l);
                    z = fmaf(rho[r * (NFEAT + 1) + aa], xs[aa], z);
                }
                float w = __builtin_amdgcn_exp2f(l * L2E);
                num = fmaf(z, w, num);
                den += w;
            }
            num += __shfl_xor(num, 16); den += __shfl_xor(den, 16);
            num += __shfl_xor(num, 32); den += __shfl_xor(den, 32);
            if (L < 16) out[tb + L] = num / (den + 1e-13f);
        }
    }
}

extern "C" void kernel_launch(void* const* d_in, const int* in_sizes, int n_in,
                              void* d_out, int out_size, void* d_ws, size_t ws_size,
                              hipStream_t stream) {
    const float* x     = (const float*)d_in[0];   // [N,16]
    const float* mu    = (const float*)d_in[1];   // [64,16]
    const float* sigma = (const float*)d_in[2];   // [64,16]
    const float* rho   = (const float*)d_in[3];   // [64,17]
    float* out = (float*)d_out;
    float* tab = (float*)d_ws;                    // 5121 dwords used

    int n = in_sizes[0] / NFEAT;                  // 131072

    fuzzy_prep<<<1, 256, 0, stream>>>(mu, sigma, rho, tab);
    int blocks = (n + 127) / 128;                 // 4 waves x 2 tiles x 16 samples
    fuzzy_main<<<blocks, 256, 0, stream>>>(x, tab, mu, sigma, rho, out, n);
}